// Round 3
// baseline (93.229 us; speedup 1.0000x reference)
//
#include <hip/hip_runtime.h>
#include <hip/hip_bf16.h>
#include <stdint.h>

#define F_FIELDS 17
#define HH 300
#define WW 400
#define H_F 38
#define W_F 50
#define PTS_PER_FIELD (H_F * W_F)     // 1900
#define RAD 13

#define TILE 16
#define TX 25                          // 400/16
#define TY 19                          // ceil(300/16) -> covers y 0..303
#define CAP 128                        // ~30 cands/tile typical; physical bound << 128

// Single fused kernel. One block per 16x16 output tile of one field.
// Phase 1: 256 threads cooperatively scan all 1900 points of the field,
//          bbox-test against the tile (coarse window test cx/cy in tile+-13),
//          and compact survivors into LDS (order nondeterministic -> only
//          reorders float adds, well under the 4.2e-3 threshold).
// Phase 2: one thread per pixel accumulates over the ~30 candidates from LDS
//          (broadcast reads), then writes min(acc + cifhr, 1) once, coalesced.
// No global atomics, no workspace, no memset: every output pixel is written
// exactly once (TX*16 == 400, TY*16 == 304 >= 300).
__global__ __launch_bounds__(256) void cifhr_fused_kernel(
    const float* __restrict__ x, const float* __restrict__ cifhr,
    float* __restrict__ out) {
    __shared__ float4 sA[CAP];   // px, py, value(=v/16), c(=-1/(16*sigma2))
    __shared__ float  sB[CAP];   // trunc2 = 4*sigma2
    __shared__ int    lcnt;

    const int tx = blockIdx.x, ty = blockIdx.y, f = blockIdx.z;
    const int tid = threadIdx.x;
    const int tx0 = tx * TILE, ty0 = ty * TILE;

    if (tid == 0) lcnt = 0;
    __syncthreads();

    // ---- Phase 1: filter + compact -------------------------------------
    const float* base = x + (size_t)(f * 5) * PTS_PER_FIELD;
    const int cxlo = tx0 - RAD, cxhi = tx0 + TILE - 1 + RAD;
    const int cylo = ty0 - RAD, cyhi = ty0 + TILE - 1 + RAD;

    for (int p = tid; p < PTS_PER_FIELD; p += 256) {
        float v = base[p];
        if (v < 0.1f) continue;                        // V_TH
        float px = base[PTS_PER_FIELD + p] * 8.0f;     // STRIDE = 8
        float py = base[2 * PTS_PER_FIELD + p] * 8.0f;
        int cx = (int)rintf(px);                       // jnp.round = half-even
        int cy = (int)rintf(py);
        // window of point = cx+-13 x cy+-13; overlap with tile?
        if (cx < cxlo || cx > cxhi || cy < cylo || cy > cyhi) continue;
        float scale = base[4 * PTS_PER_FIELD + p];
        if (!(scale * 8.0f >= 0.0f)) continue;         // MIN_SCALE = 0
        float sigma  = fmaxf(1.0f, 4.0f * scale);      // 0.5*scale*8 (pow2 exact)
        float sigma2 = sigma * sigma;
        int slot = atomicAdd(&lcnt, 1);                // LDS atomic
        if (slot < CAP) {
            sA[slot] = make_float4(px, py, v * 0.0625f, -1.0f / (16.0f * sigma2));
            sB[slot] = 4.0f * sigma2;
        }
    }
    __syncthreads();

    // ---- Phase 2: per-pixel accumulate ---------------------------------
    const int n = min(lcnt, CAP);
    const int lx = tid & 15, ly = tid >> 4;
    const int xp = tx0 + lx;
    const int yp = ty0 + ly;
    if (yp >= HH) return;                               // no barriers after this

    const float xf = (float)xp, yf = (float)yp;
    float acc = 0.0f;
    for (int k = 0; k < n; ++k) {
        float4 a = sA[k];                               // LDS broadcast
        float dx  = xf - a.x;
        float dy  = yf - a.y;
        float dx2 = dx * dx;
        float dy2 = dy * dy;
        float d2  = dy2 + dx2;                          // ref add order
        // _approx_exp(-0.5*d2/sigma2) = (1 + (-0.5*d2/sigma2)/8)^8
        float t8  = fmaf(a.w, d2, 1.0f);
        t8 = t8 * t8; t8 = t8 * t8; t8 = t8 * t8;
        float g = (dy2 < 0.25f && dx2 < 0.25f) ? 1.0f : t8;   // nearest => 1
        acc += (d2 <= sB[k]) ? a.z * g : 0.0f;          // trunc implies in-window
    }
    size_t idx = ((size_t)f * HH + yp) * WW + xp;
    out[idx] = fminf(acc + cifhr[idx], 1.0f);
}

extern "C" void kernel_launch(void* const* d_in, const int* in_sizes, int n_in,
                              void* d_out, int out_size, void* d_ws, size_t ws_size,
                              hipStream_t stream) {
    const float* cifhr = (const float*)d_in[0];
    const float* x     = (const float*)d_in[1];
    float* out = (float*)d_out;

    dim3 grid(TX, TY, F_FIELDS);   // 25 x 19 x 17 = 8075 blocks
    cifhr_fused_kernel<<<grid, 256, 0, stream>>>(x, cifhr, out);
}

// Round 4
// 81.843 us; speedup vs baseline: 1.1391x; 1.1391x over previous
//
#include <hip/hip_runtime.h>
#include <hip/hip_bf16.h>
#include <stdint.h>

#define F_FIELDS 17
#define HH 300
#define WW 400
#define H_F 38
#define W_F 50
#define PTS_PER_FIELD (H_F * W_F)     // 1900
#define RAD 13

// Block = 32x32 pixel region = 2x2 subtiles of 16x16. 256 threads.
// Grid 13 x 10 x 17 = 2210 blocks (covers 416x320 >= 400x300).
#define GX 13
#define GY 10
#define CAP 64     // per-16x16-subtile candidate cap; rp-tight lists avg ~18, max ~40

// Single fused kernel, one dispatch, no workspace, no global atomics.
// Phase 1: 256 threads scan the field's 1900 points ONCE per 32x32 block
//          (hoisted independent loads -> no dependent-load stall chain),
//          bin survivors into the 2x2 per-subtile LDS lists using the
//          per-point truncation radius rp = min(13, floor(2*sigma+0.5))
//          (d2 <= 4*sigma^2 requires |xx-px| <= 2*sigma, |px-cx| <= 0.5).
// Phase 2: each thread owns one pixel per 16x16 subtile; loops the subtile's
//          candidate list (LDS broadcast reads), exact d2 <= 4*sigma^2 gate
//          (same float compare as reference), writes min(acc+cifhr,1) once.
__global__ __launch_bounds__(256) void cifhr_fused_kernel(
    const float* __restrict__ x, const float* __restrict__ cifhr,
    float* __restrict__ out) {
    __shared__ float4 sA[4][CAP];   // px, py, value(=v/16), c(=-1/(16*sigma2))
    __shared__ float  sB[4][CAP];   // trunc2 = 4*sigma2 (exact, pow2 mul)
    __shared__ int    cnt[4];

    const int tid = threadIdx.x;
    const int f = blockIdx.z;
    const int X0 = blockIdx.x * 32;
    const int Y0 = blockIdx.y * 32;
    // last valid subtile index in each dim for this block (handles edges)
    const int sxmax = min(1, (WW - 1 - X0) >> 4);
    const int symax = min(1, (HH - 1 - Y0) >> 4);
    const int xvhi = X0 + ((sxmax + 1) << 4) - 1;   // last valid x covered
    const int yvhi = Y0 + ((symax + 1) << 4) - 1;

    if (tid < 4) cnt[tid] = 0;
    __syncthreads();

    // ---- Phase 1: scan + bin -------------------------------------------
    const float* base = x + (size_t)(f * 5) * PTS_PER_FIELD;
    for (int p = tid; p < PTS_PER_FIELD; p += 256) {
        // hoisted, independent loads (planar layout) — one vmcnt batch
        float v  = base[p];
        float xr = base[PTS_PER_FIELD + p];
        float yr = base[2 * PTS_PER_FIELD + p];
        float sc = base[4 * PTS_PER_FIELD + p];
        if (!(v >= 0.1f) || !(sc * 8.0f >= 0.0f)) continue;  // V_TH, MIN_SCALE
        float px = xr * 8.0f;                  // STRIDE = 8 (exact pow2)
        float py = yr * 8.0f;
        int cx = (int)rintf(px);               // jnp.round = half-even
        int cy = (int)rintf(py);
        float sigma  = fmaxf(1.0f, 4.0f * sc); // 0.5*scale*8
        float sigma2 = sigma * sigma;
        // per-point bbox radius; min(...,13) keeps the reference's hard 27x27 cap
        int rp = min(RAD, (int)(2.0f * sigma + 0.5f));
        int xlo = cx - rp, xhi = cx + rp;
        int ylo = cy - rp, yhi = cy + rp;
        if (xhi < X0 || xlo > xvhi || yhi < Y0 || ylo > yvhi) continue;
        int sx0 = max(0, (xlo - X0) >> 4), sx1 = min(sxmax, (xhi - X0) >> 4);
        int sy0 = max(0, (ylo - Y0) >> 4), sy1 = min(symax, (yhi - Y0) >> 4);
        float4 rec = make_float4(px, py, v * 0.0625f, -1.0f / (16.0f * sigma2));
        float tr = 4.0f * sigma2;
        for (int sy = sy0; sy <= sy1; ++sy)
            for (int sx = sx0; sx <= sx1; ++sx) {
                int s = sy * 2 + sx;
                int slot = atomicAdd(&cnt[s], 1);   // LDS atomic
                if (slot < CAP) { sA[s][slot] = rec; sB[s][slot] = tr; }
            }
    }
    __syncthreads();

    // ---- Phase 2: per-pixel accumulate over subtile lists --------------
    const int lx = tid & 15, lyr = tid >> 4;
    #pragma unroll
    for (int s = 0; s < 4; ++s) {
        int sx = s & 1, sy = s >> 1;
        if (sx > sxmax || sy > symax) continue;        // uniform branch
        int xp = X0 + (sx << 4) + lx;                  // always < 400 (400%16==0)
        int yp = Y0 + (sy << 4) + lyr;
        if (yp >= HH) continue;                        // no barriers in phase 2
        int n = min(cnt[s], CAP);
        float xf = (float)xp, yf = (float)yp;
        float acc = 0.0f;
        #pragma unroll 2
        for (int k = 0; k < n; ++k) {
            float4 a = sA[s][k];                       // LDS broadcast
            float tr = sB[s][k];
            float dx  = xf - a.x;
            float dy  = yf - a.y;
            float dx2 = dx * dx;
            float dy2 = dy * dy;
            float d2  = dy2 + dx2;                     // ref add order
            // _approx_exp(-0.5*d2/sigma2) = (1 + (-0.5*d2/sigma2)/8)^8
            float t8 = fmaf(a.w, d2, 1.0f);
            t8 = t8 * t8; t8 = t8 * t8; t8 = t8 * t8;
            float g = (dy2 < 0.25f && dx2 < 0.25f) ? 1.0f : t8;
            acc += (d2 <= tr) ? a.z * g : 0.0f;        // exact ref gate
        }
        size_t idx = ((size_t)f * HH + yp) * WW + xp;
        out[idx] = fminf(acc + cifhr[idx], 1.0f);
    }
}

extern "C" void kernel_launch(void* const* d_in, const int* in_sizes, int n_in,
                              void* d_out, int out_size, void* d_ws, size_t ws_size,
                              hipStream_t stream) {
    const float* cifhr = (const float*)d_in[0];
    const float* x     = (const float*)d_in[1];
    float* out = (float*)d_out;

    dim3 grid(GX, GY, F_FIELDS);   // 13 x 10 x 17 = 2210 blocks
    cifhr_fused_kernel<<<grid, 256, 0, stream>>>(x, cifhr, out);
}

// Round 5
// 79.707 us; speedup vs baseline: 1.1696x; 1.0268x over previous
//
#include <hip/hip_runtime.h>
#include <hip/hip_bf16.h>
#include <stdint.h>

#define F_FIELDS 17
#define HH 300
#define WW 400
#define H_F 38
#define W_F 50
#define PTS_PER_FIELD (H_F * W_F)     // 1900
#define RAD 13

// Block = 32x32 pixel region = 2x2 subtiles of 16x16. 256 threads.
// Grid 13 x 10 x 17 = 2210 blocks (covers 416x320 >= 400x300).
#define GX 13
#define GY 10
#define CAP 80     // per-subtile cap; rp-tight lists avg ~18, jittered-grid bound ~40

// Single fused kernel, one dispatch, no workspace, no global atomics.
//
// Phase 1: 256 threads scan the field's 1900 points once per 32x32 block
//          (hoisted independent loads), bin survivors into 2x2 per-subtile
//          LDS lists using per-point radius rp = min(13, floor(2*sigma+0.5)).
// Phase 2: wave s (of 4) owns subtile s; each lane owns a 2x2 pixel patch.
//          One ds_read_b128 + ds_read_b32 per candidate per WAVE now feeds
//          4 pixels (round-4 bottleneck was the DS pipe at 1 px/lane and
//          4 waves re-reading each subtile list -> 4x DS amplification).
//          Exact reference gate d2 <= 4*sigma^2; min(acc+cifhr,1) written
//          once per pixel as aligned float2 pairs.
__global__ __launch_bounds__(256) void cifhr_fused_kernel(
    const float* __restrict__ x, const float* __restrict__ cifhr,
    float* __restrict__ out) {
    __shared__ float4 sA[4][CAP];   // px, py, value(=v/16), c(=-1/(16*sigma2))
    __shared__ float  sB[4][CAP];   // trunc2 = 4*sigma2 (exact, pow2 mul)
    __shared__ int    cnt[4];

    const int tid = threadIdx.x;
    const int f = blockIdx.z;
    const int X0 = blockIdx.x * 32;
    const int Y0 = blockIdx.y * 32;
    const int sxmax = min(1, (WW - 1 - X0) >> 4);   // last valid subtile col
    const int symax = min(1, (HH - 1 - Y0) >> 4);   // last valid subtile row
    const int xvhi = X0 + ((sxmax + 1) << 4) - 1;
    const int yvhi = Y0 + ((symax + 1) << 4) - 1;

    if (tid < 4) cnt[tid] = 0;
    __syncthreads();

    // ---- Phase 1: scan + bin -------------------------------------------
    const float* base = x + (size_t)(f * 5) * PTS_PER_FIELD;
    for (int p = tid; p < PTS_PER_FIELD; p += 256) {
        float v  = base[p];                     // hoisted independent loads
        float xr = base[PTS_PER_FIELD + p];
        float yr = base[2 * PTS_PER_FIELD + p];
        float sc = base[4 * PTS_PER_FIELD + p];
        if (!(v >= 0.1f) || !(sc * 8.0f >= 0.0f)) continue;  // V_TH, MIN_SCALE
        float px = xr * 8.0f;                   // STRIDE = 8 (exact pow2)
        float py = yr * 8.0f;
        int cx = (int)rintf(px);                // jnp.round = half-even
        int cy = (int)rintf(py);
        float sigma  = fmaxf(1.0f, 4.0f * sc);  // 0.5*scale*8
        float sigma2 = sigma * sigma;
        // d2 <= 4*sigma^2 requires |xx-cx| <= floor(2*sigma+0.5); cap at 13
        int rp = min(RAD, (int)(2.0f * sigma + 0.5f));
        int xlo = cx - rp, xhi = cx + rp;
        int ylo = cy - rp, yhi = cy + rp;
        if (xhi < X0 || xlo > xvhi || yhi < Y0 || ylo > yvhi) continue;
        int sx0 = max(0, (xlo - X0) >> 4), sx1 = min(sxmax, (xhi - X0) >> 4);
        int sy0 = max(0, (ylo - Y0) >> 4), sy1 = min(symax, (yhi - Y0) >> 4);
        float4 rec = make_float4(px, py, v * 0.0625f, -1.0f / (16.0f * sigma2));
        float tr = 4.0f * sigma2;
        for (int sy = sy0; sy <= sy1; ++sy)
            for (int sx = sx0; sx <= sx1; ++sx) {
                int s = sy * 2 + sx;
                int slot = atomicAdd(&cnt[s], 1);   // LDS atomic
                if (slot < CAP) { sA[s][slot] = rec; sB[s][slot] = tr; }
            }
    }
    __syncthreads();

    // ---- Phase 2: wave s -> subtile s, lane -> 2x2 pixel patch ----------
    const int s  = tid >> 6;           // wave index = subtile index
    const int ln = tid & 63;
    const int sx = s & 1, sy = s >> 1;
    if (sx > sxmax || sy > symax) return;            // wave-uniform exit

    const int xb = X0 + (sx << 4) + ((ln & 7) << 1); // even
    const int yb = Y0 + (sy << 4) + ((ln >> 3) << 1);
    const float xf0 = (float)xb,  xf1 = (float)(xb + 1);
    const float yf0 = (float)yb,  yf1 = (float)(yb + 1);

    const int n = min(cnt[s], CAP);
    float a00 = 0.0f, a01 = 0.0f, a10 = 0.0f, a11 = 0.0f;
    for (int k = 0; k < n; ++k) {
        float4 a = sA[s][k];                         // LDS broadcast, 1/wave
        float tr = sB[s][k];
        float dx0 = xf0 - a.x, dx1 = xf1 - a.x;
        float dy0 = yf0 - a.y, dy1 = yf1 - a.y;
        float dx0s = dx0 * dx0, dx1s = dx1 * dx1;
        float dy0s = dy0 * dy0, dy1s = dy1 * dy1;
        {   // (y0, x0)
            float d2 = dy0s + dx0s;
            float t8 = fmaf(a.w, d2, 1.0f); t8 *= t8; t8 *= t8; t8 *= t8;
            float g  = (fmaxf(dy0s, dx0s) < 0.25f) ? 1.0f : t8;
            a00 += (d2 <= tr) ? a.z * g : 0.0f;
        }
        {   // (y0, x1)
            float d2 = dy0s + dx1s;
            float t8 = fmaf(a.w, d2, 1.0f); t8 *= t8; t8 *= t8; t8 *= t8;
            float g  = (fmaxf(dy0s, dx1s) < 0.25f) ? 1.0f : t8;
            a01 += (d2 <= tr) ? a.z * g : 0.0f;
        }
        {   // (y1, x0)
            float d2 = dy1s + dx0s;
            float t8 = fmaf(a.w, d2, 1.0f); t8 *= t8; t8 *= t8; t8 *= t8;
            float g  = (fmaxf(dy1s, dx0s) < 0.25f) ? 1.0f : t8;
            a10 += (d2 <= tr) ? a.z * g : 0.0f;
        }
        {   // (y1, x1)
            float d2 = dy1s + dx1s;
            float t8 = fmaf(a.w, d2, 1.0f); t8 *= t8; t8 *= t8; t8 *= t8;
            float g  = (fmaxf(dy1s, dx1s) < 0.25f) ? 1.0f : t8;
            a11 += (d2 <= tr) ? a.z * g : 0.0f;
        }
    }

    // ---- epilogue: aligned float2 writes, each pixel exactly once -------
    if (yb < HH) {
        size_t idx = ((size_t)f * HH + yb) * WW + xb;
        const float2 c = *(const float2*)(cifhr + idx);
        float2 o;
        o.x = fminf(a00 + c.x, 1.0f);
        o.y = fminf(a01 + c.y, 1.0f);
        *(float2*)(out + idx) = o;
    }
    if (yb + 1 < HH) {
        size_t idx = ((size_t)f * HH + yb + 1) * WW + xb;
        const float2 c = *(const float2*)(cifhr + idx);
        float2 o;
        o.x = fminf(a10 + c.x, 1.0f);
        o.y = fminf(a11 + c.y, 1.0f);
        *(float2*)(out + idx) = o;
    }
}

extern "C" void kernel_launch(void* const* d_in, const int* in_sizes, int n_in,
                              void* d_out, int out_size, void* d_ws, size_t ws_size,
                              hipStream_t stream) {
    const float* cifhr = (const float*)d_in[0];
    const float* x     = (const float*)d_in[1];
    float* out = (float*)d_out;

    dim3 grid(GX, GY, F_FIELDS);   // 13 x 10 x 17 = 2210 blocks
    cifhr_fused_kernel<<<grid, 256, 0, stream>>>(x, cifhr, out);
}